// Round 8
// baseline (84.889 us; speedup 1.0000x reference)
//
#include <hip/hip_runtime.h>
#include <math.h>

#define N_T 32768
#define L 65536
#define BATCH 64
#define NPAIR 32
#define NEV 8
#define NROOM 16
#define DGATE 128
#define ROWP 258
#define TP 17
#define TWO_PI 6.2831853071795864769f
#define INV_L (1.0f / 65536.0f)

__device__ __forceinline__ float2 cmul(float2 a, float2 b) {
    return make_float2(a.x * b.x - a.y * b.y, a.x * b.y + a.y * b.x);
}
// base-4 digit reversal of an 8-bit index (involution)
__device__ __forceinline__ int dr4(int p) {
    return ((p & 3) << 6) | ((p & 12) << 2) | ((p & 48) >> 2) | ((p & 192) >> 6);
}

// register radix-4 DIF butterfly (fwd)
__device__ __forceinline__ void bf4f(float2& a, float2& b, float2& c, float2& d,
                                     const float2* tw, int f, int q) {
    float2 t0 = make_float2(a.x + c.x, a.y + c.y);
    float2 t1 = make_float2(a.x - c.x, a.y - c.y);
    float2 t2 = make_float2(b.x + d.x, b.y + d.y);
    float2 u  = make_float2(b.x - d.x, b.y - d.y);
    float2 t3 = make_float2(u.y, -u.x);            // -i*u
    a = make_float2(t0.x + t2.x, t0.y + t2.y);
    b = cmul(make_float2(t1.x + t3.x, t1.y + t3.y), tw[f * q]);
    c = cmul(make_float2(t0.x - t2.x, t0.y - t2.y), tw[2 * f * q]);
    d = cmul(make_float2(t1.x - t3.x, t1.y - t3.y), tw[3 * f * q]);
}
// register radix-4 DIT butterfly (inv): exact inverse of bf4f
__device__ __forceinline__ void bf4i(float2& a, float2& b, float2& c, float2& d,
                                     const float2* tw, int f, int q) {
    float2 w1 = tw[f * q], w2 = tw[2 * f * q], w3 = tw[3 * f * q];
    float2 y0 = a;
    float2 y1 = cmul(b, make_float2(w1.x, -w1.y));
    float2 y2 = cmul(c, make_float2(w2.x, -w2.y));
    float2 y3 = cmul(d, make_float2(w3.x, -w3.y));
    float2 t0 = make_float2(y0.x + y2.x, y0.y + y2.y);
    float2 t2 = make_float2(y0.x - y2.x, y0.y - y2.y);
    float2 t1 = make_float2(y1.x + y3.x, y1.y + y3.y);
    float2 u  = make_float2(y1.x - y3.x, y1.y - y3.y);
    a = make_float2(t0.x + t1.x, t0.y + t1.y);
    b = make_float2(t2.x - u.y, t2.y + u.x);
    c = make_float2(t0.x - t1.x, t0.y - t1.y);
    d = make_float2(t2.x + u.y, t2.y - u.x);
}
__device__ __forceinline__ void bfly4_fwd(float2* A, int a0, int st, const float2* tw, int f, int q) {
    bf4f(A[a0], A[a0 + st], A[a0 + 2 * st], A[a0 + 3 * st], tw, f, q);
}
__device__ __forceinline__ void bfly4_inv(float2* A, int a0, int st, const float2* tw, int f, int q) {
    bf4i(A[a0], A[a0 + st], A[a0 + 2 * st], A[a0 + 3 * st], tw, f, q);
}

// ---- gating ----
__global__ void k_prep(const float* __restrict__ g, const float* __restrict__ w_room,
                       const float* __restrict__ b_room, const float* __restrict__ w_mix,
                       const float* __restrict__ b_mix,
                       float* __restrict__ wroom, float* __restrict__ mixv) {
    int b = threadIdx.x;
    if (b >= BATCH) return;
    float logits[NROOM];
    for (int r = 0; r < NROOM; r++) logits[r] = b_room[r];
    float acc_mix = b_mix[0];
    for (int d = 0; d < DGATE; d++) {
        float gv = g[b * DGATE + d];
        for (int r = 0; r < NROOM; r++) logits[r] += gv * w_room[d * NROOM + r];
        acc_mix += gv * w_mix[d];
    }
    float m = logits[0];
    for (int r = 1; r < NROOM; r++) m = fmaxf(m, logits[r]);
    float s = 0.f;
    for (int r = 0; r < NROOM; r++) { logits[r] = expf(logits[r] - m); s += logits[r]; }
    float inv = 1.f / s;
    for (int r = 0; r < NROOM; r++) wroom[b * NROOM + r] = logits[r] * inv;
    mixv[b] = 1.f / (1.f + expf(-acc_mix));
}

// ---- K_b(t) = sum_r wroom[b][r] * rooms[r][t], written once (8 MB) ----
__global__ void k_kmix(const float* __restrict__ rooms, const float* __restrict__ wroom,
                       float* __restrict__ Kbuf) {
    int gid = blockIdx.x * blockDim.x + threadIdx.x;   // BATCH * N_T/4
    int b = gid >> 13;
    int q = gid & 8191;
    int t0 = q << 2;
    const float* wb = wroom + b * NROOM;
    float4 kk = make_float4(0.f, 0.f, 0.f, 0.f);
#pragma unroll
    for (int r = 0; r < NROOM; r++) {
        float w = wb[r];
        float4 rv = *(const float4*)(rooms + (size_t)r * N_T + t0);
        kk.x += w * rv.x; kk.y += w * rv.y; kk.z += w * rv.z; kk.w += w * rv.w;
    }
    *(float4*)(Kbuf + (size_t)b * N_T + t0) = kk;
}

// ---- fused: stage dry tile (events gather) + K tile, write dryf, register radix-4
// fwd col FFT with two-round half-LDS transpose, + big twiddle ----
__global__ void k_fwd(const float* __restrict__ events, const int* __restrict__ indices,
                      const float* __restrict__ Kbuf,
                      float* __restrict__ dryf, float2* __restrict__ C) {
    __shared__ float2 T[128 * TP];       // 17.4 KB; front 16 KB doubles as dry/K staging
    __shared__ float2 tw[256];
    __shared__ float2 fine[256];
    int t = threadIdx.x;
    int a = blockIdx.x >> 4;             // batch
    int c0 = (blockIdx.x & 15) * 16;     // column group
    float2* base = C + (size_t)a * L;
    {
        float sv, cv;
        __sincosf(-TWO_PI * (float)t * (1.0f / 256.0f), &sv, &cv);
        tw[t] = make_float2(cv, sv);
        __sincosf(-TWO_PI * (float)t * INV_L, &sv, &cv);
        fine[t] = make_float2(cv, sv);
    }
    float* dtile = (float*)T;            // [128][16] dry
    float* ktile = dtile + 128 * 16;     // [128][16] K
    const float* eb = events + (size_t)a * NEV * N_T;
    const int* ib = indices + a * NEV;
    int n2a = t >> 2, qa = (t & 3) << 2;
    int n2b = n2a + 64;
    float4 d0 = make_float4(0.f, 0.f, 0.f, 0.f), d1 = d0;
#pragma unroll
    for (int e = 0; e < NEV; e++) {
        int s = ib[e];
        const float* er = eb + e * N_T + c0;
        if (n2a >= s) {
            float4 v = *(const float4*)(er + qa + ((n2a - s) << 8));
            d0.x += v.x; d0.y += v.y; d0.z += v.z; d0.w += v.w;
        }
        if (n2b >= s) {
            float4 v = *(const float4*)(er + qa + ((n2b - s) << 8));
            d1.x += v.x; d1.y += v.y; d1.z += v.z; d1.w += v.w;
        }
    }
    const float* Kb = Kbuf + (size_t)a * N_T + c0;
    float4 k0 = *(const float4*)(Kb + qa + (n2a << 8));
    float4 k1 = *(const float4*)(Kb + qa + (n2b << 8));
    float* db = dryf + (size_t)a * N_T + c0;
    *(float4*)(db + qa + (n2a << 8)) = d0;
    *(float4*)(db + qa + (n2b << 8)) = d1;
    *(float4*)&dtile[n2a * 16 + qa] = d0;
    *(float4*)&dtile[n2b * 16 + qa] = d1;
    *(float4*)&ktile[n2a * 16 + qa] = k0;
    *(float4*)&ktile[n2b * 16 + qa] = k1;
    __syncthreads();
    int j = t >> 4, c = t & 15;
    int n1 = c0 + c;
    float2 r[16];
#pragma unroll
    for (int m = 0; m < 8; m++) {
        int n2 = j + 16 * m;
        r[m] = make_float2(dtile[n2 * 16 + c], ktile[n2 * 16 + c]);
    }
#pragma unroll
    for (int m = 8; m < 16; m++) r[m] = make_float2(0.f, 0.f);
    // stages 1-2 in registers
#pragma unroll
    for (int m0 = 0; m0 < 4; m0++) bf4f(r[m0], r[m0 + 4], r[m0 + 8], r[m0 + 12], tw, 1, j + 16 * m0);
#pragma unroll
    for (int h = 0; h < 4; h++) bf4f(r[4 * h], r[4 * h + 1], r[4 * h + 2], r[4 * h + 3], tw, 4, j);
    __syncthreads();                     // staging reads done; T reusable
    // two-round transpose through 128-row buffer
    float2 r2[16];
#pragma unroll
    for (int m = 0; m < 8; m++) T[(j + 16 * m) * TP + c] = r[m];      // rows 0..127
    __syncthreads();
    if (j < 8) {
#pragma unroll
        for (int jj = 0; jj < 16; jj++) r2[jj] = T[(jj + 16 * j) * TP + c];
    }
    __syncthreads();
#pragma unroll
    for (int m = 8; m < 16; m++) T[(j + 16 * m - 128) * TP + c] = r[m];  // rows 128..255
    __syncthreads();
    if (j >= 8) {
#pragma unroll
        for (int jj = 0; jj < 16; jj++) r2[jj] = T[(jj + 16 * (j - 8)) * TP + c];
    }
    // stages 3-4
#pragma unroll
    for (int q = 0; q < 4; q++) bf4f(r2[q], r2[q + 4], r2[q + 8], r2[q + 12], tw, 16, q);
#pragma unroll
    for (int h = 0; h < 4; h++) bf4f(r2[4 * h], r2[4 * h + 1], r2[4 * h + 2], r2[4 * h + 3], tw, 64, 0);
#pragma unroll
    for (int jj = 0; jj < 16; jj++) {
        int p = jj + 16 * j;
        int k2 = dr4(p);
        int ph = (n1 * k2) & (L - 1);
        float2 w = cmul(tw[ph >> 8], fine[ph & 255]);
        base[n1 + (p << 8)] = cmul(r2[jj], w);
    }
}

// ---- pointwise unit (LDS form) ----
__device__ __forceinline__ void pw_unit(float2* A, int sJ, int kJ, int sN, int kN) {
    float2 Z0j = A[sJ * ROWP + kJ],       Z0n = A[sN * ROWP + kN];
    float2 Z1j = A[(4 + sJ) * ROWP + kJ], Z1n = A[(4 + sN) * ROWP + kN];
    float2 D0 = make_float2(0.5f * (Z0j.x + Z0n.x), 0.5f * (Z0j.y - Z0n.y));
    float2 K0 = make_float2(0.5f * (Z0j.y + Z0n.y), 0.5f * (Z0n.x - Z0j.x));
    float2 D1 = make_float2(0.5f * (Z1j.x + Z1n.x), 0.5f * (Z1j.y - Z1n.y));
    float2 K1 = make_float2(0.5f * (Z1j.y + Z1n.y), 0.5f * (Z1n.x - Z1j.x));
    float2 W0 = cmul(D0, K0);
    float2 W1 = cmul(D1, K1);
    A[sJ * ROWP + kJ] = make_float2(W0.x - W1.y, W0.y + W1.x);
    A[sN * ROWP + kN] = make_float2(W0.x + W1.y, W1.x - W0.y);
}

// ---- fused row pass: fwd radix-4 DIF (8 rows) -> pointwise -> inv DIT (4 rows) ----
__global__ void k_rowpw(float2* __restrict__ C) {
    __shared__ float2 A[8 * ROWP];
    __shared__ float2 tw[192];
    int t = threadIdx.x;
    int p = blockIdx.x >> 6;
    int g = blockIdx.x & 63;
    int rows[4];
    if (g == 0) { rows[0] = 0; rows[1] = 1; rows[2] = 128; rows[3] = 255; }
    else        { rows[0] = 2 * g; rows[1] = 2 * g + 1; rows[2] = 256 - 2 * g; rows[3] = 255 - 2 * g; }
    if (t < 192) {
        float sv, cv;
        __sincosf(-TWO_PI * (float)t * (1.0f / 256.0f), &sv, &cv);
        tw[t] = make_float2(cv, sv);
    }
    float2* b0 = C + (size_t)(2 * p) * L;
    float2* b1 = b0 + L;
    for (int u = t; u < 1024; u += 256) {
        int slot = u >> 7;
        int f = (u & 127) << 1;
        const float2* arr = (slot < 4) ? b0 : b1;
        int grow = dr4(rows[slot & 3]);
        float4 v = *(const float4*)(arr + (grow << 8) + f);
        *(float4*)&A[slot * ROWP + f] = v;
    }
    __syncthreads();
#pragma unroll
    for (int lm = 8; lm >= 6; lm -= 2) {
        int Q = 1 << (lm - 2), f = 256 >> lm;
        for (int u = t; u < 512; u += 256) {
            int row = u >> 6, qi = u & 63;
            int q = qi & (Q - 1);
            int i0 = ((qi - q) << 2) + q;
            bfly4_fwd(A, row * ROWP + i0, Q, tw, f, q);
        }
        __syncthreads();
    }
#pragma unroll
    for (int lm = 4; lm >= 2; lm -= 2) {
        int Q = 1 << (lm - 2), f = 256 >> lm;
        for (int u = t; u < 512; u += 256) {
            int row = u & 7, qi = u >> 3;
            int q = qi & (Q - 1);
            int i0 = ((qi - q) << 2) + q;
            bfly4_fwd(A, row * ROWP + i0, Q, tw, f, q);
        }
        __syncthreads();
    }
    if (g) {
        pw_unit(A, 0, t, 2, 255 - t);
    } else {
        if (t == 0)      { pw_unit(A, 0, 0, 0, 0); pw_unit(A, 0, 2, 0, 2); }
        else if (t < 128) pw_unit(A, 0, dr4(t), 0, dr4(256 - t));
        else              { int qq = t - 128; pw_unit(A, 2, qq, 2, 255 - qq); }
    }
    pw_unit(A, 1, t, 3, 255 - t);
    __syncthreads();
#pragma unroll
    for (int lm = 2; lm <= 4; lm += 2) {
        int Q = 1 << (lm - 2), f = 256 >> lm;
        int row = t & 3, qi = t >> 2;
        int q = qi & (Q - 1);
        int i0 = ((qi - q) << 2) + q;
        bfly4_inv(A, row * ROWP + i0, Q, tw, f, q);
        __syncthreads();
    }
#pragma unroll
    for (int lm = 6; lm <= 8; lm += 2) {
        int Q = 1 << (lm - 2), f = 256 >> lm;
        int row = t >> 6, qi = t & 63;
        int q = qi & (Q - 1);
        int i0 = ((qi - q) << 2) + q;
        bfly4_inv(A, row * ROWP + i0, Q, tw, f, q);
        __syncthreads();
    }
    for (int u = t; u < 512; u += 256) {
        int slot = u >> 7;
        int f = (u & 127) << 1;
        int r = rows[slot];
        float2 va = A[slot * ROWP + f];
        float2 vb = A[slot * ROWP + f + 1];
        int pha = (f * r) & (L - 1);
        int phb = ((f + 1) * r) & (L - 1);
        float sa, ca, sb, cb2;
        __sincosf(TWO_PI * (float)pha * INV_L, &sa, &ca);
        __sincosf(TWO_PI * (float)phb * INV_L, &sb, &cb2);
        float2 ra = cmul(va, make_float2(ca, sa));
        float2 rb = cmul(vb, make_float2(cb2, sb));
        *(float4*)(b0 + (dr4(r) << 8) + f) = make_float4(ra.x, ra.y, rb.x, rb.y);
    }
}

// ---- inverse col pass (register, two-round transpose): stages 1,4 | T | 16,64; mix+max ----
__global__ void k_fft_col_inv(float2* __restrict__ C, const float* __restrict__ dryf,
                              const float* __restrict__ mixv, float* __restrict__ out,
                              float* __restrict__ partial) {
    __shared__ float2 T[128 * TP];
    __shared__ float2 tw[256];
    __shared__ float sm0[4], sm1[4];
    int t = threadIdx.x;
    int a = blockIdx.x >> 4;
    int cbg = blockIdx.x & 15;
    int c0 = cbg * 16;
    float2* base = C + (size_t)(2 * a) * L;
    {
        float sv, cv;
        __sincosf(-TWO_PI * (float)t * (1.0f / 256.0f), &sv, &cv);
        tw[t] = make_float2(cv, sv);
    }
    int j = t >> 4, c = t & 15;
    int n1 = c0 + c;
    float2 r[16];
#pragma unroll
    for (int jj = 0; jj < 16; jj++) r[jj] = base[n1 + ((jj + 16 * j) << 8)];
    __syncthreads();
#pragma unroll
    for (int h = 0; h < 4; h++) bf4i(r[4 * h], r[4 * h + 1], r[4 * h + 2], r[4 * h + 3], tw, 64, 0);
#pragma unroll
    for (int q = 0; q < 4; q++) bf4i(r[q], r[q + 4], r[q + 8], r[q + 12], tw, 16, q);
    // two-round transpose
    float2 r2[16];
    if (j < 8) {
#pragma unroll
        for (int jj = 0; jj < 16; jj++) T[(jj + 16 * j) * TP + c] = r[jj];   // rows 0..127
    }
    __syncthreads();
#pragma unroll
    for (int m = 0; m < 8; m++) r2[m] = T[(j + 16 * m) * TP + c];
    __syncthreads();
    if (j >= 8) {
#pragma unroll
        for (int jj = 0; jj < 16; jj++) T[(16 * (j - 8) + jj) * TP + c] = r[jj];  // rows 128..255
    }
    __syncthreads();
#pragma unroll
    for (int m = 8; m < 16; m++) r2[m] = T[(j + 16 * (m - 8)) * TP + c];
#pragma unroll
    for (int h = 0; h < 4; h++) bf4i(r2[4 * h], r2[4 * h + 1], r2[4 * h + 2], r2[4 * h + 3], tw, 4, j);
#pragma unroll
    for (int m0 = 0; m0 < 4; m0++) bf4i(r2[m0], r2[m0 + 4], r2[m0 + 8], r2[m0 + 12], tw, 1, j + 16 * m0);
    int b0 = 2 * a, b1 = 2 * a + 1;
    float mix0 = mixv[b0], mix1 = mixv[b1];
    float om0 = 1.f - mix0, om1 = 1.f - mix1;
    const float* dry0 = dryf + (size_t)b0 * N_T;
    const float* dry1 = dryf + (size_t)b1 * N_T;
    float* out0 = out + (size_t)b0 * N_T;
    float* out1 = out + (size_t)b1 * N_T;
    float m0 = -3.4e38f, m1 = -3.4e38f;
#pragma unroll
    for (int m = 0; m < 8; m++) {
        int pos = n1 + ((j + 16 * m) << 8);
        float d0 = dry0[pos], d1 = dry1[pos];
        float o0 = mix0 * (r2[m].x * INV_L) + om0 * d0;
        float o1 = mix1 * (r2[m].y * INV_L) + om1 * d1;
        out0[pos] = o0;
        out1[pos] = o1;
        m0 = fmaxf(m0, o0);
        m1 = fmaxf(m1, o1);
    }
#pragma unroll
    for (int off = 32; off > 0; off >>= 1) {
        m0 = fmaxf(m0, __shfl_down(m0, off));
        m1 = fmaxf(m1, __shfl_down(m1, off));
    }
    if ((t & 63) == 0) { sm0[t >> 6] = m0; sm1[t >> 6] = m1; }
    __syncthreads();
    if (t == 0) {
        partial[b0 * 16 + cbg] = fmaxf(fmaxf(sm0[0], sm0[1]), fmaxf(sm0[2], sm0[3]));
        partial[b1 * 16 + cbg] = fmaxf(fmaxf(sm1[0], sm1[1]), fmaxf(sm1[2], sm1[3]));
    }
}

__global__ void k_norm(float* __restrict__ out, const float* __restrict__ partial) {
    int blk = blockIdx.x;
    int b = blk >> 5;
    int ch = blk & 31;
    __shared__ float smx;
    if (threadIdx.x < 16) {
        float p = partial[b * 16 + threadIdx.x];
#pragma unroll
        for (int off = 8; off > 0; off >>= 1) p = fmaxf(p, __shfl_down(p, off, 16));
        if (threadIdx.x == 0) smx = p;
    }
    __syncthreads();
    float inv = 1.f / (smx + 1e-8f);
    size_t base = (size_t)b * N_T + ch * 1024 + threadIdx.x * 4;
    float4 o = *(const float4*)(out + base);
    o.x *= inv; o.y *= inv; o.z *= inv; o.w *= inv;
    *(float4*)(out + base) = o;
}

extern "C" void kernel_launch(void* const* d_in, const int* in_sizes, int n_in,
                              void* d_out, int out_size, void* d_ws, size_t ws_size,
                              hipStream_t stream) {
    const float* events = (const float*)d_in[0];
    const int* indices = (const int*)d_in[1];
    const float* g      = (const float*)d_in[2];
    const float* rooms  = (const float*)d_in[3];
    const float* w_room = (const float*)d_in[4];
    const float* b_room = (const float*)d_in[5];
    const float* w_mix  = (const float*)d_in[6];
    const float* b_mix  = (const float*)d_in[7];
    float* out = (float*)d_out;

    char* ws = (char*)d_ws;
    float2* C = (float2*)ws;  // [64][65536] complex: Z_b = dry_b + i*K_b (spectral)
    size_t off = (size_t)BATCH * L * sizeof(float2);
    float* dryf = (float*)(ws + off);
    off += (size_t)BATCH * N_T * sizeof(float);
    float* Kbuf = (float*)(ws + off);
    off += (size_t)BATCH * N_T * sizeof(float);
    float* wroom = (float*)(ws + off);
    off += BATCH * NROOM * sizeof(float);
    float* mixv = (float*)(ws + off);
    off += BATCH * sizeof(float);
    float* partial = (float*)(ws + off);

    k_prep<<<1, 64, 0, stream>>>(g, w_room, b_room, w_mix, b_mix, wroom, mixv);
    k_kmix<<<BATCH * (N_T / 4) / 256, 256, 0, stream>>>(rooms, wroom, Kbuf);
    k_fwd<<<BATCH * 16, 256, 0, stream>>>(events, indices, Kbuf, dryf, C);
    k_rowpw<<<NPAIR * 64, 256, 0, stream>>>(C);
    k_fft_col_inv<<<NPAIR * 16, 256, 0, stream>>>(C, dryf, mixv, out, partial);
    k_norm<<<BATCH * 32, 256, 0, stream>>>(out, partial);
}